// Round 10
// baseline (430.517 us; speedup 1.0000x reference)
//
#include <hip/hip_runtime.h>
#include <hip/hip_bf16.h>
#include <stdint.h>

typedef __attribute__((ext_vector_type(8))) short short8;
typedef __attribute__((ext_vector_type(4))) float f32x4;

#define D 256

static __device__ __forceinline__ float b2f(unsigned short u) {
  union { unsigned u; float f; } c; c.u = ((unsigned)u) << 16; return c.f;
}
static __device__ __forceinline__ unsigned f2b(float f) {
  union { float f; unsigned u; } c; c.f = f;
  return (c.u + 0x7FFFu + ((c.u >> 16) & 1u)) >> 16;
}

// async global->LDS, 16B per lane, wave-uniform LDS base + lane*16
static __device__ __forceinline__ void gload16(const void* g, void* l) {
  __builtin_amdgcn_global_load_lds(
      (const __attribute__((address_space(1))) unsigned int*)g,
      (__attribute__((address_space(3))) unsigned int*)l, 16, 0, 0);
}

// ---- d1: cvt x (fp32->bf16, pad) | cvt W -> Wt2[o][r*256+i] | deg2 atomics
__global__ void k_cvt_deg2(const float* __restrict__ x, unsigned short* __restrict__ xb,
                           long n_elems, long pad_elems, int xblocks,
                           const float* __restrict__ w, unsigned short* __restrict__ wt2,
                           int wblocks,
                           const int* __restrict__ ei, const int* __restrict__ et,
                           int* deg, int E) {
  int bx = blockIdx.x;
  if (bx < xblocks) {
    long i4 = (long)bx * 256 + threadIdx.x;
    if (i4 * 4 >= pad_elems) return;
    ushort4 o;
    if (i4 * 4 < n_elems) {
      float4 v = ((const float4*)x)[i4];
      o.x = f2b(v.x); o.y = f2b(v.y); o.z = f2b(v.z); o.w = f2b(v.w);
    } else {
      o.x = 0; o.y = 0; o.z = 0; o.w = 0;
    }
    ((ushort4*)xb)[i4] = o;
  } else if (bx < xblocks + wblocks) {
    // Wt2[o][k], k = r*256+i  (true column order; no permute anywhere)
    int q = (bx - xblocks) * 256 + threadIdx.x;
    int k = q & 2047, o = q >> 11;
    int r = k >> 8, i = k & 255;
    wt2[q] = (unsigned short)f2b(w[((size_t)(r * 256 + i)) * 256 + o]);
  } else {
    int e = (bx - xblocks - wblocks) * 256 + threadIdx.x;
    if (e < E) atomicAdd(&deg[ei[e] * 8 + et[e]], 1);
  }
}

// ---- d2: per-256-chunk reduce of deg2 -> bsum -----------------------------
__global__ void k_scan1(const int* __restrict__ deg, int* bsum, int n) {
  __shared__ int sm[256];
  int t = threadIdx.x, idx = blockIdx.x * 256 + t;
  sm[t] = idx < n ? deg[idx] : 0;
  __syncthreads();
  for (int off = 128; off; off >>= 1) {
    if (t < off) sm[t] += sm[t + off];
    __syncthreads();
  }
  if (t == 0) bsum[blockIdx.x] = sm[0];
}

// ---- d3: fused global scan: every block redundantly scans bsum (nsc<=1792,
// 7 per thread), then local exclusive scan of its deg chunk -> rp2/cursor.
__global__ void k_scan23b(const int* __restrict__ deg, const int* __restrict__ bsum,
                          int* rp2, int* cursor, int nsc, int n) {
  __shared__ int sm[256];
  __shared__ int sboff[1792];
  int t = threadIdx.x;
  int loc[7];
  int s = 0;
#pragma unroll
  for (int j = 0; j < 7; ++j) {
    int idx = t * 7 + j;
    loc[j] = s;
    s += (idx < nsc) ? bsum[idx] : 0;
  }
  sm[t] = s;
  __syncthreads();
  for (int off = 1; off < 256; off <<= 1) {
    int xv = t >= off ? sm[t - off] : 0;
    __syncthreads();
    sm[t] += xv;
    __syncthreads();
  }
  int base = sm[t] - s;
#pragma unroll
  for (int j = 0; j < 7; ++j) sboff[t * 7 + j] = base + loc[j];
  int total = sm[255];
  __syncthreads();
  int boff = sboff[blockIdx.x];
  int idx = blockIdx.x * 256 + t;
  int v = idx < n ? deg[idx] : 0;
  sm[t] = v;
  __syncthreads();
  for (int off = 1; off < 256; off <<= 1) {
    int xv = t >= off ? sm[t - off] : 0;
    __syncthreads();
    sm[t] += xv;
    __syncthreads();
  }
  if (idx < n) {
    int e0 = boff + sm[t] - v;
    rp2[idx] = e0;
    cursor[idx] = e0;
  }
  if (blockIdx.x == 0 && t == 0) rp2[n] = total;
}

// ---- d4: scatter-bin by key=(row*8+type) -> ecol --------------------------
__global__ void k_bin2(const int* __restrict__ ei, const int* __restrict__ et,
                       int* cursor, int* ecol, int E) {
  int e = blockIdx.x * 256 + threadIdx.x;
  if (e >= E) return;
  int key = ei[e] * 8 + et[e];
  int pos = atomicAdd(&cursor[key], 1);
  ecol[pos] = ei[E + e];
}

// ---- d5: aggregate H[bin][:] = sum_{edges in bin} xb[col][:] --------------
// One wave per bin (4/block, 100k blocks). Random reads hit xb (25.6 MB,
// L3-resident); H write coalesced 512B/wave. Pad bins (>= n2) write zeros.
__global__ __launch_bounds__(256) void k_agg(const int* __restrict__ rp2,
                                             const int* __restrict__ ecol,
                                             const unsigned short* __restrict__ xb,
                                             unsigned short* __restrict__ H,
                                             int n2, int nbins) {
  const int lane = threadIdx.x & 63;
  const int bin = blockIdx.x * 4 + (threadIdx.x >> 6);
  if (bin >= nbins) return;
  float a0 = 0.f, a1 = 0.f, a2 = 0.f, a3 = 0.f;
  if (bin < n2) {
    int s = rp2[bin], e = rp2[bin + 1];
    for (int i = s; i < e; ++i) {
      int col = ecol[i];
      ushort4 v = *(const ushort4*)(xb + (size_t)col * 256 + lane * 4);
      a0 += b2f(v.x); a1 += b2f(v.y); a2 += b2f(v.z); a3 += b2f(v.w);
    }
  }
  ushort4 pk;
  pk.x = (unsigned short)f2b(a0);
  pk.y = (unsigned short)f2b(a1);
  pk.z = (unsigned short)f2b(a2);
  pk.w = (unsigned short)f2b(a3);
  *(ushort4*)(H + (size_t)bin * 256 + lane * 4) = pk;
}

// ---- d6: GEMM  out = relu(bias + H_flat[Mpad][2048] @ Wt2^T[2048][256]) ---
// H_flat = H viewed [Mpad][2048] (bins are (row,rel) key-major => contiguous).
// Block: 64 rows x full N=256, K-loop 32 steps of 64. 4 waves, wave-tile
// 64m x 64n (acc 4x4). LDS 40KB -> 4 blocks/CU, grid 782 fully co-resident.
// Staging via gload16, linear LDS dest + inverse-swizzled source (chunk ^
// row&7), swizzled ds_read — all verbatim from the proven k_gemm patterns.
__global__ __launch_bounds__(256) void k_gemm2(const unsigned short* __restrict__ H,
                                               const unsigned short* __restrict__ Wt2,
                                               const float* __restrict__ bias,
                                               float* __restrict__ out, int Nn) {
  __shared__ __align__(16) char lA[64 * 128];    // [64 rows][8 chunks of 16B]
  __shared__ __align__(16) char lB[256 * 128];   // [256 rows][8 chunks of 16B]
  const int t = threadIdx.x;
  const int lane = t & 63;
  const int wave = t >> 6;
  const int l15 = lane & 15, lhi = lane >> 4;
  const size_t tm = (size_t)blockIdx.x * 64;

  f32x4 acc[4][4];
#pragma unroll
  for (int a = 0; a < 4; ++a)
#pragma unroll
    for (int b = 0; b < 4; ++b)
#pragma unroll
      for (int e = 0; e < 4; ++e) acc[a][b][e] = 0.f;

  for (int kt = 0; kt < 2048; kt += 64) {
    __syncthreads();  // previous k-step's readers done
#pragma unroll
    for (int it = 0; it < 2; ++it) {   // A: 512 chunks, 2/thread
      int s = it * 256 + t;
      int row = s >> 3, c = s & 7;
      gload16(H + (tm + row) * 2048 + kt + ((c ^ (row & 7)) * 8),
              lA + (it * 256 + wave * 64) * 16);
    }
#pragma unroll
    for (int it = 0; it < 8; ++it) {   // B: 2048 chunks, 8/thread
      int s = it * 256 + t;
      int row = s >> 3, c = s & 7;
      gload16(Wt2 + (size_t)row * 2048 + kt + ((c ^ (row & 7)) * 8),
              lB + (it * 256 + wave * 64) * 16);
    }
    __syncthreads();  // barrier drain waits vmcnt(0): lA/lB ready

    short8 af[4][2];
#pragma unroll
    for (int mi = 0; mi < 4; ++mi)
#pragma unroll
      for (int kk = 0; kk < 2; ++kk) {
        int R = mi * 16 + l15;
        int c = kk * 4 + lhi;
        af[mi][kk] = *(const short8*)(lA + R * 128 + ((c ^ (R & 7)) * 16));
      }
#pragma unroll
    for (int ni = 0; ni < 4; ++ni) {
      int R2 = wave * 64 + ni * 16 + l15;
      short8 b0 = *(const short8*)(lB + R2 * 128 + ((lhi ^ (R2 & 7)) * 16));
      short8 b1 = *(const short8*)(lB + R2 * 128 + (((4 + lhi) ^ (R2 & 7)) * 16));
#pragma unroll
      for (int mi = 0; mi < 4; ++mi) {
        acc[mi][ni] = __builtin_amdgcn_mfma_f32_16x16x32_bf16(af[mi][0], b0, acc[mi][ni], 0, 0, 0);
        acc[mi][ni] = __builtin_amdgcn_mfma_f32_16x16x32_bf16(af[mi][1], b1, acc[mi][ni], 0, 0, 0);
      }
    }
  }
  // fused epilogue: bias + relu, direct f32 stores (16 lanes = 64B segments)
#pragma unroll
  for (int ni = 0; ni < 4; ++ni) {
    int col = wave * 64 + ni * 16 + l15;
    float bb = bias[col];
#pragma unroll
    for (int mi = 0; mi < 4; ++mi) {
#pragma unroll
      for (int j = 0; j < 4; ++j) {
        size_t row = tm + mi * 16 + lhi * 4 + j;
        if (row < (size_t)Nn)
          out[row * 256 + col] = fmaxf(acc[mi][ni][j] + bb, 0.f);
      }
    }
  }
}

extern "C" void kernel_launch(void* const* d_in, const int* in_sizes, int n_in,
                              void* d_out, int out_size, void* d_ws, size_t ws_size,
                              hipStream_t stream) {
  const float* x = (const float*)d_in[0];
  const int* ei = (const int*)d_in[1];
  const int* et = (const int*)d_in[2];
  const float* w = (const float*)d_in[3];
  const float* bias = (const float*)d_in[4];
  float* out = (float*)d_out;

  const int Nn = in_sizes[0] / D;        // 50000
  const int E = in_sizes[2];             // 800000
  const int R = in_sizes[3] / (D * D);   // 8
  const int Mpad = ((Nn + 63) / 64) * 64;   // 50048
  const int n2 = Nn * R;                 // 400000 real bins
  const int nbins = Mpad * R;            // 400384 padded bins

  char* p = (char*)d_ws;
  auto alloc = [&](size_t bytes) -> char* {
    char* q = p;
    p += (bytes + 255) & ~(size_t)255;
    return q;
  };
  unsigned short* H = (unsigned short*)alloc((size_t)nbins * 256 * 2);  // 205 MB
  unsigned short* xb = (unsigned short*)alloc((size_t)Nn * D * 2);
  unsigned short* wt2 = (unsigned short*)alloc((size_t)256 * 2048 * 2);
  int* rp2 = (int*)alloc((size_t)(n2 + 1) * 4);
  int* cursor2 = (int*)alloc((size_t)n2 * 4);
  int* deg2 = (int*)alloc((size_t)n2 * 4);
  int* bsum = (int*)alloc(1792 * 4);
  int* ecol = (int*)alloc((size_t)E * 4);

  const int nsc2 = (n2 + 255) / 256;     // 1563 (<= 1792)
  const int xblocks = (Nn * D) / 1024 + 1;  // fp32->bf16, 1024 elems/block
  const int xblocks4 = (((Nn * D) + 1023) / 1024);
  const int wblocks = (256 * 2048) / 256;   // 2048
  const int eblocks = (E + 255) / 256;      // 3125
  (void)xblocks;

  hipMemsetAsync(deg2, 0, (size_t)n2 * 4, stream);

  // d1: cvt-x | cvt-W | degree atomics
  hipLaunchKernelGGL(k_cvt_deg2, dim3(xblocks4 + wblocks + eblocks), dim3(256), 0, stream,
                     x, xb, (long)Nn * D, (long)Nn * D, xblocks4,
                     w, wt2, wblocks, ei, et, deg2, E);
  // d2/d3: scan chain
  hipLaunchKernelGGL(k_scan1, dim3(nsc2), dim3(256), 0, stream, deg2, bsum, n2);
  hipLaunchKernelGGL(k_scan23b, dim3(nsc2), dim3(256), 0, stream, deg2, bsum,
                     rp2, cursor2, nsc2, n2);
  // d4: scatter-bin
  hipLaunchKernelGGL(k_bin2, dim3(eblocks), dim3(256), 0, stream, ei, et, cursor2, ecol, E);
  // d5: aggregate H
  hipLaunchKernelGGL(k_agg, dim3(nbins / 4), dim3(256), 0, stream, rp2, ecol, xb,
                     H, n2, nbins);
  // d6: GEMM + bias + relu -> out
  hipLaunchKernelGGL(k_gemm2, dim3(Mpad / 64), dim3(256), 0, stream, H, wt2, bias, out, Nn);
}